// Round 4
// baseline (215.424 us; speedup 1.0000x reference)
//
#include <hip/hip_runtime.h>
#include <hip/hip_cooperative_groups.h>
#include <math.h>

namespace cg = cooperative_groups;

// y_t = clamp(y_{t-1}, x_t, x_t+1): play operator as associative clamp-scan.
// compose(l, r) = "apply l first, then r". min/max/med3-only => exact =>
// any regrouping is bit-identical (deterministic).
//
// Single cooperative kernel: input lives in REGISTERS across a grid sync, so
// it is read exactly once and output written exactly once (128 MB total HBM).

#define TPB 256
#define EPT 64
#define EPB (TPB * EPT)     // 16384 elements per block
#define NBLK 1024           // 4 blocks/CU x 256 CU, co-resident (coop launch)

struct Pair { float a, b; };

__device__ __forceinline__ float med3f(float x, float lo, float hi) {
    return __builtin_amdgcn_fmed3f(x, lo, hi);   // = clamp(x, lo, hi), lo<=hi
}
__device__ __forceinline__ Pair compose(Pair l, Pair r) {
    Pair o; o.a = med3f(l.a, r.a, r.b); o.b = med3f(l.b, r.a, r.b); return o;
}
__device__ __forceinline__ Pair ident() {
    Pair p; p.a = -INFINITY; p.b = INFINITY; return p;
}

// =================== single-pass cooperative kernel ========================
__global__ __launch_bounds__(TPB, 4)
void k_coop(const float* __restrict__ in, const float* __restrict__ kptr,
            float* __restrict__ agg_a, float* __restrict__ agg_b,
            float* __restrict__ out, int n) {
    const int tid  = threadIdx.x;
    const int lane = tid & 63;
    const int wid  = tid >> 6;
    const int vid  = blockIdx.x;
    const int base = vid * EPB + tid * EPT;
    const float k  = kptr[0];
    __shared__ Pair wagg[TPB / 64];

    // ---- phase A: load 64 elements into registers, fold ordered aggregate
    float xs[EPT];
    const bool full = (base + EPT <= n);
    Pair p = ident();
    if (full) {
        #pragma unroll
        for (int v = 0; v < EPT / 4; ++v) {
            float4 f = reinterpret_cast<const float4*>(in + base)[v];
            xs[4*v+0] = f.x; xs[4*v+1] = f.y; xs[4*v+2] = f.z; xs[4*v+3] = f.w;
        }
        #pragma unroll
        for (int j = 0; j < EPT; ++j) {
            float lo = xs[j] * k, hi = lo + 1.0f;
            if (j == 0 && base == 0) { lo = xs[0]; hi = xs[0]; }  // constant p0
            p.a = med3f(p.a, lo, hi);
            p.b = med3f(p.b, lo, hi);
        }
    } else {
        #pragma unroll
        for (int j = 0; j < EPT; ++j)               // static j: registers only
            xs[j] = (base + j < n) ? in[base + j] : 0.0f;
        #pragma unroll
        for (int j = 0; j < EPT; ++j) {
            if (base + j < n) {
                float lo = xs[j] * k, hi = lo + 1.0f;
                if (j == 0 && base == 0) { lo = xs[0]; hi = xs[0]; }
                p.a = med3f(p.a, lo, hi);
                p.b = med3f(p.b, lo, hi);
            }
        }
    }

    // wave inclusive scan of thread aggregates
    Pair w = p;
    #pragma unroll
    for (int off = 1; off < 64; off <<= 1) {
        Pair u; u.a = __shfl_up(w.a, off); u.b = __shfl_up(w.b, off);
        if (lane >= off) w = compose(u, w);
    }
    if (lane == 63) wagg[wid] = w;
    __syncthreads();
    Pair wpre = ident();
    #pragma unroll
    for (int i = 0; i < TPB / 64; ++i) if (i < wid) wpre = compose(wpre, wagg[i]);
    Pair up; up.a = __shfl_up(w.a, 1); up.b = __shfl_up(w.b, 1);
    Pair ex = (lane == 0) ? wpre : compose(wpre, up);   // excl within block

    if (tid == TPB - 1) {   // wpre(3) ∘ w = full block aggregate
        Pair bagg = compose(wpre, w);
        __hip_atomic_store(agg_a + vid, bagg.a, __ATOMIC_RELAXED, __HIP_MEMORY_SCOPE_AGENT);
        __hip_atomic_store(agg_b + vid, bagg.b, __ATOMIC_RELAXED, __HIP_MEMORY_SCOPE_AGENT);
    }

    cg::this_grid().sync();

    // ---- phase B: exclusive prefix over agg[0..vid-1] (redundant per block)
    Pair q = ident();
    if (vid > 0) {
        const int seg = (vid + TPB - 1) >> 8;       // <= 4
        const int lo  = tid * seg;
        const int hi  = min(lo + seg, vid);
        float va[4], vb[4];
        #pragma unroll
        for (int u2 = 0; u2 < 4; ++u2) {            // issue all loads first
            const int i = lo + u2;
            const bool ok = (i < hi);
            va[u2] = ok ? __hip_atomic_load(agg_a + i, __ATOMIC_RELAXED, __HIP_MEMORY_SCOPE_AGENT)
                        : -INFINITY;
            vb[u2] = ok ? __hip_atomic_load(agg_b + i, __ATOMIC_RELAXED, __HIP_MEMORY_SCOPE_AGENT)
                        :  INFINITY;
        }
        #pragma unroll
        for (int u2 = 0; u2 < 4; ++u2) {            // ordered compose
            Pair r; r.a = va[u2]; r.b = vb[u2];
            q = compose(q, r);
        }
    }
    Pair wq = q;
    #pragma unroll
    for (int off = 1; off < 64; off <<= 1) {
        Pair u; u.a = __shfl_up(wq.a, off); u.b = __shfl_up(wq.b, off);
        if (lane >= off) wq = compose(u, wq);
    }
    if (lane == 63) wagg[wid] = wq;                 // grid.sync covered reuse
    __syncthreads();
    Pair E = wagg[0];
    #pragma unroll
    for (int i = 1; i < TPB / 64; ++i) E = compose(E, wagg[i]);

    // ---- phase C: apply from registers, write once
    Pair fin = compose(E, ex);
    float y = med3f(0.0f, fin.a, fin.b);   // any prefix containing elem 0 is
                                           // constant, so the seed 0 is inert
    if (full) {
        #pragma unroll
        for (int v = 0; v < EPT / 4; ++v) {
            float o0, o1, o2, o3;
            { float lo = xs[4*v+0] * k, hi = lo + 1.0f;
              if (v == 0 && base == 0) { lo = xs[0]; hi = xs[0]; }
              y = med3f(y, lo, hi); o0 = y; }
            { float lo = xs[4*v+1] * k, hi = lo + 1.0f; y = med3f(y, lo, hi); o1 = y; }
            { float lo = xs[4*v+2] * k, hi = lo + 1.0f; y = med3f(y, lo, hi); o2 = y; }
            { float lo = xs[4*v+3] * k, hi = lo + 1.0f; y = med3f(y, lo, hi); o3 = y; }
            reinterpret_cast<float4*>(out + base)[v] = make_float4(o0, o1, o2, o3);
        }
    } else {
        #pragma unroll
        for (int j = 0; j < EPT; ++j) {
            if (base + j < n) {
                float lo = xs[j] * k, hi = lo + 1.0f;
                if (j == 0 && base == 0) { lo = xs[0]; hi = xs[0]; }
                y = med3f(y, lo, hi);
                out[base + j] = y;
            }
        }
    }

    // leftover elements beyond NBLK*EPB: globally-last thread continues chain
    const long long covered = (long long)NBLK * EPB;
    if (vid == NBLK - 1 && tid == TPB - 1 && covered < (long long)n) {
        for (long long e = covered; e < (long long)n; ++e) {
            float xv = in[e] * k;
            y = med3f(y, xv, xv + 1.0f);   // e > 0 always here
            out[e] = y;
        }
    }
}

// =================== fallback: 2-kernel path (no coop) =====================
#define FEPT 16
#define FEPB (TPB * FEPT)

__global__ __launch_bounds__(TPB)
void k_reduce_fb(const float* __restrict__ in, const float* __restrict__ kptr,
                 float2* __restrict__ agg, int n) {
    const float k = kptr[0];
    const int tid = threadIdx.x, lane = tid & 63, wid = tid >> 6;
    const int base = blockIdx.x * FEPB + tid * FEPT;
    Pair p = ident();
    if (base + FEPT <= n) {
        #pragma unroll
        for (int v = 0; v < FEPT / 4; ++v) {
            float4 f = reinterpret_cast<const float4*>(in + base)[v];
            float xv[4] = {f.x, f.y, f.z, f.w};
            #pragma unroll
            for (int j = 0; j < 4; ++j) {
                float lo = xv[j] * k, hi = lo + 1.0f;
                if (v == 0 && j == 0 && base == 0) { lo = xv[0]; hi = xv[0]; }
                p.a = med3f(p.a, lo, hi); p.b = med3f(p.b, lo, hi);
            }
        }
    } else {
        #pragma unroll
        for (int j = 0; j < FEPT; ++j) {
            if (base + j < n) {
                float x = in[base + j];
                float lo = x * k, hi = lo + 1.0f;
                if (j == 0 && base == 0) { lo = x; hi = x; }
                p.a = med3f(p.a, lo, hi); p.b = med3f(p.b, lo, hi);
            }
        }
    }
    Pair w = p;
    #pragma unroll
    for (int off = 1; off < 64; off <<= 1) {
        Pair u; u.a = __shfl_up(w.a, off); u.b = __shfl_up(w.b, off);
        if (lane >= off) w = compose(u, w);
    }
    __shared__ Pair wagg[TPB / 64];
    if (lane == 63) wagg[wid] = w;
    __syncthreads();
    if (tid == 0) {
        Pair b = wagg[0];
        #pragma unroll
        for (int i = 1; i < TPB / 64; ++i) b = compose(b, wagg[i]);
        agg[blockIdx.x] = make_float2(b.a, b.b);
    }
}

__global__ __launch_bounds__(TPB)
void k_apply_fb(const float* __restrict__ in, const float* __restrict__ kptr,
                const float2* __restrict__ agg, float* __restrict__ out, int n) {
    const float k = kptr[0];
    const int tid = threadIdx.x, lane = tid & 63, wid = tid >> 6;
    const int vid = blockIdx.x;
    const int base = vid * FEPB + tid * FEPT;

    float xs[FEPT];
    const bool full = (base + FEPT <= n);
    if (full) {
        #pragma unroll
        for (int v = 0; v < FEPT / 4; ++v) {
            float4 f = reinterpret_cast<const float4*>(in + base)[v];
            xs[4*v+0] = f.x; xs[4*v+1] = f.y; xs[4*v+2] = f.z; xs[4*v+3] = f.w;
        }
    } else {
        #pragma unroll
        for (int j = 0; j < FEPT; ++j)
            xs[j] = (base + j < n) ? in[base + j] : 0.0f;
    }

    Pair p = ident();
    if (vid > 0) {
        const int seg = (vid + TPB - 1) >> 8;
        const int lo  = tid * seg;
        const int hi  = min(lo + seg, vid);
        for (int i = lo; i < hi; ++i) {
            float2 g = agg[i];
            Pair r; r.a = g.x; r.b = g.y;
            p = compose(p, r);
        }
    }
    Pair w = p;
    #pragma unroll
    for (int off = 1; off < 64; off <<= 1) {
        Pair u; u.a = __shfl_up(w.a, off); u.b = __shfl_up(w.b, off);
        if (lane >= off) w = compose(u, w);
    }
    __shared__ Pair wpre4[TPB / 64];
    if (lane == 63) wpre4[wid] = w;
    __syncthreads();
    Pair E = wpre4[0];
    #pragma unroll
    for (int i = 1; i < TPB / 64; ++i) E = compose(E, wpre4[i]);

    Pair tp = ident();
    #pragma unroll
    for (int j = 0; j < FEPT; ++j) {
        if (base + j < n) {
            float lo = xs[j] * k, hi = lo + 1.0f;
            if (j == 0 && base == 0) { lo = xs[0]; hi = xs[0]; }
            tp.a = med3f(tp.a, lo, hi); tp.b = med3f(tp.b, lo, hi);
        }
    }
    Pair tw = tp;
    #pragma unroll
    for (int off = 1; off < 64; off <<= 1) {
        Pair u; u.a = __shfl_up(tw.a, off); u.b = __shfl_up(tw.b, off);
        if (lane >= off) tw = compose(u, tw);
    }
    __shared__ Pair wagg2[TPB / 64];
    if (lane == 63) wagg2[wid] = tw;
    __syncthreads();
    Pair wpref = ident();
    #pragma unroll
    for (int i = 0; i < TPB / 64; ++i) if (i < wid) wpref = compose(wpref, wagg2[i]);
    Pair up; up.a = __shfl_up(tw.a, 1); up.b = __shfl_up(tw.b, 1);
    Pair excl = (lane == 0) ? wpref : compose(wpref, up);

    Pair fin = compose(E, excl);
    float y = med3f(0.0f, fin.a, fin.b);

    if (full) {
        #pragma unroll
        for (int v = 0; v < FEPT / 4; ++v) {
            float o[4];
            #pragma unroll
            for (int jj = 0; jj < 4; ++jj) {
                float lo = xs[4*v+jj] * k, hi = lo + 1.0f;
                if (v == 0 && jj == 0 && base == 0) { lo = xs[0]; hi = xs[0]; }
                y = med3f(y, lo, hi);
                o[jj] = y;
            }
            reinterpret_cast<float4*>(out + base)[v] = make_float4(o[0], o[1], o[2], o[3]);
        }
    } else {
        #pragma unroll
        for (int j = 0; j < FEPT; ++j) {
            if (base + j < n) {
                float lo = xs[j] * k, hi = lo + 1.0f;
                if (j == 0 && base == 0) { lo = xs[0]; hi = xs[0]; }
                y = med3f(y, lo, hi);
                out[base + j] = y;
            }
        }
    }
}

// ========================== host launcher ==================================
extern "C" void kernel_launch(void* const* d_in, const int* in_sizes, int n_in,
                              void* d_out, int out_size, void* d_ws, size_t ws_size,
                              hipStream_t stream) {
    const float* in   = (const float*)d_in[0];   // [T+1], in[0] = p0
    const float* kptr = (const float*)d_in[1];   // scalar weight
    float* out = (float*)d_out;                  // [T+1]
    const int n = in_sizes[0];

    float* agg_a = (float*)d_ws;                 // NBLK floats
    float* agg_b = agg_a + NBLK;                 // NBLK floats

    void* args[] = { (void*)&in, (void*)&kptr, (void*)&agg_a, (void*)&agg_b,
                     (void*)&out, (void*)&n };
    hipError_t err = hipLaunchCooperativeKernel((const void*)k_coop,
                                                dim3(NBLK), dim3(TPB),
                                                args, 0, stream);
    if (err != hipSuccess) {
        // deterministic fallback: two-pass path, no cooperative features
        const int nb = (n + FEPB - 1) / FEPB;
        float2* agg = (float2*)d_ws;
        k_reduce_fb<<<nb, TPB, 0, stream>>>(in, kptr, agg, n);
        k_apply_fb <<<nb, TPB, 0, stream>>>(in, kptr, agg, out, n);
    }
}

// Round 6
// 96.715 us; speedup vs baseline: 2.2274x; 2.2274x over previous
//
#include <hip/hip_runtime.h>
#include <math.h>

// y_t = clamp(y_{t-1}, x_t, x_t+1): play operator as associative clamp-scan.
// compose(l, r) = "apply l first, then r" = clamp l's window by r's window.
// min/max/med3-only => exact => any regrouping is bit-identical (deterministic).
//
// Two passes, no atomics:
//   pass 1 (k_reduce): per-block ordered aggregate -> agg[nb] (32 KB, L2/L3)
//   pass 2 (k_apply) : each block redundantly composes its exclusive prefix
//                      over agg[] with PIPELINED loads (no dependent-load
//                      chain), applies the clamp chain, NT-stores the output
//                      so the input stays Infinity-Cache-resident.

#define TPB 256
#define EPT 16
#define EPB (TPB * EPT)   // 4096 elements per block

typedef float floatx4 __attribute__((ext_vector_type(4)));  // NT-store-able

struct Pair { float a, b; };

__device__ __forceinline__ float med3f(float x, float lo, float hi) {
    return __builtin_amdgcn_fmed3f(x, lo, hi);   // clamp(x, lo, hi), lo<=hi
}
__device__ __forceinline__ Pair compose(Pair l, Pair r) {
    Pair o; o.a = med3f(l.a, r.a, r.b); o.b = med3f(l.b, r.a, r.b); return o;
}
__device__ __forceinline__ Pair ident() {
    Pair p; p.a = -INFINITY; p.b = INFINITY; return p;
}

// ---------------- pass 1: per-block ordered aggregate ----------------------
__global__ __launch_bounds__(TPB)
void k_reduce(const float* __restrict__ in, const float* __restrict__ kptr,
              float2* __restrict__ agg, int n) {
    const float k = kptr[0];
    const int tid = threadIdx.x, lane = tid & 63, wid = tid >> 6;
    const int base = blockIdx.x * EPB + tid * EPT;

    float xs[EPT];
    const bool full = (base + EPT <= n);
    if (full) {
        #pragma unroll
        for (int v = 0; v < EPT / 4; ++v) {
            float4 f = reinterpret_cast<const float4*>(in + base)[v];
            xs[4*v+0] = f.x; xs[4*v+1] = f.y; xs[4*v+2] = f.z; xs[4*v+3] = f.w;
        }
    } else {
        #pragma unroll
        for (int j = 0; j < EPT; ++j)          // static j: registers only
            xs[j] = (base + j < n) ? in[base + j] : 0.0f;
    }

    Pair p = ident();
    #pragma unroll
    for (int j = 0; j < EPT; ++j) {
        if (base + j < n) {
            float lo = xs[j] * k, hi = lo + 1.0f;
            if (j == 0 && base == 0) { lo = xs[0]; hi = xs[0]; }  // constant p0
            p.a = med3f(p.a, lo, hi);
            p.b = med3f(p.b, lo, hi);
        }
    }

    // ordered tree-reduce within wave (adjacent pairing preserves order);
    // lane 0 ends with the wave aggregate.
    Pair v = p;
    #pragma unroll
    for (int off = 1; off < 64; off <<= 1) {
        Pair u; u.a = __shfl_down(v.a, off); u.b = __shfl_down(v.b, off);
        Pair c = compose(v, u);
        if (lane + off < 64) v = c;
    }
    __shared__ Pair wagg[TPB / 64];
    if (lane == 0) wagg[wid] = v;
    __syncthreads();
    if (tid == 0) {
        Pair b = wagg[0];
        #pragma unroll
        for (int i = 1; i < TPB / 64; ++i) b = compose(b, wagg[i]);
        agg[blockIdx.x] = make_float2(b.a, b.b);
    }
}

// ---------------- pass 2: pipelined redundant prefix + apply ---------------
__global__ __launch_bounds__(TPB)
void k_apply(const float* __restrict__ in, const float* __restrict__ kptr,
             const float2* __restrict__ agg, float* __restrict__ out, int n) {
    const float k = kptr[0];
    const int tid = threadIdx.x, lane = tid & 63, wid = tid >> 6;
    const int vid = blockIdx.x;
    const int base = vid * EPB + tid * EPT;

    // 1) issue input loads first (L3-resident in steady state)
    float xs[EPT];
    const bool full = (base + EPT <= n);
    if (full) {
        #pragma unroll
        for (int v = 0; v < EPT / 4; ++v) {
            float4 f = reinterpret_cast<const float4*>(in + base)[v];
            xs[4*v+0] = f.x; xs[4*v+1] = f.y; xs[4*v+2] = f.z; xs[4*v+3] = f.w;
        }
    } else {
        #pragma unroll
        for (int j = 0; j < EPT; ++j)          // static j: registers only
            xs[j] = (base + j < n) ? in[base + j] : 0.0f;
    }

    // 2) exclusive block prefix E over agg[0..vid): loads issued in
    //    predicated batches of 8 (independent), THEN composed -> no
    //    dependent-load chain. seg==16 covers vid <= 4096; dynamic tail
    //    (scalars only, no arrays) handles larger grids.
    Pair q = ident();
    {
        const int segd = (vid + TPB - 1) >> 8;          // ceil(vid/256)
        const int seg  = segd > 16 ? segd : 16;
        const int lo   = tid * seg;
        #pragma unroll
        for (int b8 = 0; b8 < 2; ++b8) {
            float ga[8], gb[8];
            #pragma unroll
            for (int i = 0; i < 8; ++i) {               // issue 8 loads
                const int idx = lo + b8 * 8 + i;
                float2 g = (idx < vid) ? agg[idx]
                                       : make_float2(-INFINITY, INFINITY);
                ga[i] = g.x; gb[i] = g.y;
            }
            #pragma unroll
            for (int i = 0; i < 8; ++i) {               // then compose
                Pair r; r.a = ga[i]; r.b = gb[i];
                q = compose(q, r);
            }
        }
        const int hi = (lo + seg < vid) ? lo + seg : vid;
        for (int i = lo + 16; i < hi; ++i) {            // dead for nb<=4097
            float2 g = agg[i];
            Pair r; r.a = g.x; r.b = g.y;
            q = compose(q, r);
        }
    }
    // ordered tree-reduce across the block -> E (same value in all threads)
    Pair v2 = q;
    #pragma unroll
    for (int off = 1; off < 64; off <<= 1) {
        Pair u; u.a = __shfl_down(v2.a, off); u.b = __shfl_down(v2.b, off);
        Pair c = compose(v2, u);
        if (lane + off < 64) v2 = c;
    }
    __shared__ Pair wE[TPB / 64];
    if (lane == 0) wE[wid] = v2;
    __syncthreads();
    Pair E = wE[0];
    #pragma unroll
    for (int i = 1; i < TPB / 64; ++i) E = compose(E, wE[i]);

    // 3) intra-block exclusive prefix over thread aggregates
    Pair tp = ident();
    #pragma unroll
    for (int j = 0; j < EPT; ++j) {
        if (base + j < n) {
            float lo = xs[j] * k, hi = lo + 1.0f;
            if (j == 0 && base == 0) { lo = xs[0]; hi = xs[0]; }
            tp.a = med3f(tp.a, lo, hi);
            tp.b = med3f(tp.b, lo, hi);
        }
    }
    Pair w = tp;
    #pragma unroll
    for (int off = 1; off < 64; off <<= 1) {
        Pair u; u.a = __shfl_up(w.a, off); u.b = __shfl_up(w.b, off);
        if (lane >= off) w = compose(u, w);
    }
    __shared__ Pair wS[TPB / 64];
    if (lane == 63) wS[wid] = w;
    __syncthreads();
    Pair wpre = ident();
    #pragma unroll
    for (int i = 0; i < TPB / 64; ++i) if (i < wid) wpre = compose(wpre, wS[i]);
    Pair up; up.a = __shfl_up(w.a, 1); up.b = __shfl_up(w.b, 1);
    Pair ex = (lane == 0) ? wpre : compose(wpre, up);

    // 4) apply from registers, non-temporal stores (don't evict input from L3)
    Pair fin = compose(E, ex);
    float y = med3f(0.0f, fin.a, fin.b);  // any prefix containing elem 0 is
                                          // constant (a==b): seed 0 is inert
    if (full) {
        #pragma unroll
        for (int v = 0; v < EPT / 4; ++v) {
            float o0, o1, o2, o3;
            { float lo = xs[4*v+0] * k, hi = lo + 1.0f;
              if (v == 0 && base == 0) { lo = xs[0]; hi = xs[0]; }
              y = med3f(y, lo, hi); o0 = y; }
            { float lo = xs[4*v+1] * k, hi = lo + 1.0f; y = med3f(y, lo, hi); o1 = y; }
            { float lo = xs[4*v+2] * k, hi = lo + 1.0f; y = med3f(y, lo, hi); o2 = y; }
            { float lo = xs[4*v+3] * k, hi = lo + 1.0f; y = med3f(y, lo, hi); o3 = y; }
            floatx4 ov; ov.x = o0; ov.y = o1; ov.z = o2; ov.w = o3;
            __builtin_nontemporal_store(ov,
                reinterpret_cast<floatx4*>(out + base) + v);
        }
    } else {
        #pragma unroll
        for (int j = 0; j < EPT; ++j) {
            if (base + j < n) {
                float lo = xs[j] * k, hi = lo + 1.0f;
                if (j == 0 && base == 0) { lo = xs[0]; hi = xs[0]; }
                y = med3f(y, lo, hi);
                __builtin_nontemporal_store(y, out + base + j);
            }
        }
    }
}

// ========================== host launcher ==================================
extern "C" void kernel_launch(void* const* d_in, const int* in_sizes, int n_in,
                              void* d_out, int out_size, void* d_ws, size_t ws_size,
                              hipStream_t stream) {
    const float* in   = (const float*)d_in[0];   // [T+1], in[0] = p0
    const float* kptr = (const float*)d_in[1];   // scalar weight
    float* out = (float*)d_out;                  // [T+1]
    const int n  = in_sizes[0];
    const int nb = (n + EPB - 1) / EPB;          // 4097 for T = 2^24

    float2* agg = (float2*)d_ws;                 // nb aggregates (32 KB)

    k_reduce<<<nb, TPB, 0, stream>>>(in, kptr, agg, n);
    k_apply <<<nb, TPB, 0, stream>>>(in, kptr, agg, out, n);
}

// Round 7
// 49.539 us; speedup vs baseline: 4.3486x; 1.9523x over previous
//
#include <hip/hip_runtime.h>
#include <math.h>

// y_t = clamp(y_{t-1}, x_t, x_t+1): play operator as associative clamp-scan.
// compose(l, r) = "apply l first, then r" = clamp l's window by r's window.
// min/max/med3-only => exact => any regrouping is bit-identical (deterministic).
//
// Two passes, no atomics:
//   pass 1 (k_reduce): per-block ordered aggregate -> agg[nb] (16 KB, L2)
//   pass 2 (k_apply) : each block redundantly composes its exclusive prefix
//                      over agg[] (one batch of 8 independent L2 loads per
//                      thread), applies the clamp chain, cached float4 stores
//                      (L2 merges the 64B-stride partials; NT stores measured
//                      2.4x write amplification in round 6 -- do not use).

#define TPB 256
#define EPT 32
#define EPB (TPB * EPT)   // 8192 elements per block -> nb = 2049 for T=2^24

struct Pair { float a, b; };

__device__ __forceinline__ float med3f(float x, float lo, float hi) {
    return __builtin_amdgcn_fmed3f(x, lo, hi);   // clamp(x, lo, hi), lo<=hi
}
__device__ __forceinline__ Pair compose(Pair l, Pair r) {
    Pair o; o.a = med3f(l.a, r.a, r.b); o.b = med3f(l.b, r.a, r.b); return o;
}
__device__ __forceinline__ Pair ident() {
    Pair p; p.a = -INFINITY; p.b = INFINITY; return p;
}

// ---------------- pass 1: per-block ordered aggregate ----------------------
__global__ __launch_bounds__(TPB)
void k_reduce(const float* __restrict__ in, const float* __restrict__ kptr,
              float2* __restrict__ agg, int n) {
    const float k = kptr[0];
    const int tid = threadIdx.x, lane = tid & 63, wid = tid >> 6;
    const int base = blockIdx.x * EPB + tid * EPT;

    Pair p = ident();
    const bool full = (base + EPT <= n);
    if (full) {
        #pragma unroll
        for (int v = 0; v < EPT / 4; ++v) {
            float4 f = reinterpret_cast<const float4*>(in + base)[v];
            float xv[4] = {f.x, f.y, f.z, f.w};
            #pragma unroll
            for (int j = 0; j < 4; ++j) {
                float lo = xv[j] * k, hi = lo + 1.0f;
                if (v == 0 && j == 0 && base == 0) { lo = xv[0]; hi = xv[0]; }
                p.a = med3f(p.a, lo, hi);
                p.b = med3f(p.b, lo, hi);
            }
        }
    } else {
        #pragma unroll
        for (int j = 0; j < EPT; ++j) {         // static j: registers only
            if (base + j < n) {
                float x = in[base + j];
                float lo = x * k, hi = lo + 1.0f;
                if (j == 0 && base == 0) { lo = x; hi = x; }
                p.a = med3f(p.a, lo, hi);
                p.b = med3f(p.b, lo, hi);
            }
        }
    }

    // ordered tree-reduce within wave; lane 0 ends with the wave aggregate
    Pair v = p;
    #pragma unroll
    for (int off = 1; off < 64; off <<= 1) {
        Pair u; u.a = __shfl_down(v.a, off); u.b = __shfl_down(v.b, off);
        Pair c = compose(v, u);
        if (lane + off < 64) v = c;
    }
    __shared__ Pair wagg[TPB / 64];
    if (lane == 0) wagg[wid] = v;
    __syncthreads();
    if (tid == 0) {
        Pair b = wagg[0];
        #pragma unroll
        for (int i = 1; i < TPB / 64; ++i) b = compose(b, wagg[i]);
        agg[blockIdx.x] = make_float2(b.a, b.b);
    }
}

// ---------------- pass 2: pipelined redundant prefix + apply ---------------
__global__ __launch_bounds__(TPB)
void k_apply(const float* __restrict__ in, const float* __restrict__ kptr,
             const float2* __restrict__ agg, float* __restrict__ out, int n) {
    const float k = kptr[0];
    const int tid = threadIdx.x, lane = tid & 63, wid = tid >> 6;
    const int vid = blockIdx.x;
    const int base = vid * EPB + tid * EPT;

    // 1) issue input loads first (L3-resident in steady state)
    float xs[EPT];
    const bool full = (base + EPT <= n);
    if (full) {
        #pragma unroll
        for (int v = 0; v < EPT / 4; ++v) {
            float4 f = reinterpret_cast<const float4*>(in + base)[v];
            xs[4*v+0] = f.x; xs[4*v+1] = f.y; xs[4*v+2] = f.z; xs[4*v+3] = f.w;
        }
    } else {
        #pragma unroll
        for (int j = 0; j < EPT; ++j)           // static j: registers only
            xs[j] = (base + j < n) ? in[base + j] : 0.0f;
    }

    // 2) exclusive block prefix E over agg[0..vid): one batch of 8
    //    independent loads per thread (seg=8 covers vid <= 2048), then
    //    ordered compose. Dynamic scalar tail for larger grids.
    Pair q = ident();
    {
        const int segd = (vid + TPB - 1) >> 8;          // ceil(vid/256)
        const int seg  = segd > 8 ? segd : 8;
        const int lo   = tid * seg;
        float ga[8], gb[8];
        #pragma unroll
        for (int i = 0; i < 8; ++i) {                   // issue 8 loads
            const int idx = lo + i;
            float2 g = (idx < vid) ? agg[idx]
                                   : make_float2(-INFINITY, INFINITY);
            ga[i] = g.x; gb[i] = g.y;
        }
        #pragma unroll
        for (int i = 0; i < 8; ++i) {                   // then compose
            Pair r; r.a = ga[i]; r.b = gb[i];
            q = compose(q, r);
        }
        const int hi = (lo + seg < vid) ? lo + seg : vid;
        for (int i = lo + 8; i < hi; ++i) {             // dead for nb<=2049
            float2 g = agg[i];
            Pair r; r.a = g.x; r.b = g.y;
            q = compose(q, r);
        }
    }
    // ordered tree-reduce across the block -> E (same value in all threads)
    Pair v2 = q;
    #pragma unroll
    for (int off = 1; off < 64; off <<= 1) {
        Pair u; u.a = __shfl_down(v2.a, off); u.b = __shfl_down(v2.b, off);
        Pair c = compose(v2, u);
        if (lane + off < 64) v2 = c;
    }
    __shared__ Pair wE[TPB / 64];
    if (lane == 0) wE[wid] = v2;
    __syncthreads();
    Pair E = wE[0];
    #pragma unroll
    for (int i = 1; i < TPB / 64; ++i) E = compose(E, wE[i]);

    // 3) intra-block exclusive prefix over thread aggregates
    Pair tp = ident();
    #pragma unroll
    for (int j = 0; j < EPT; ++j) {
        if (base + j < n) {
            float lo = xs[j] * k, hi = lo + 1.0f;
            if (j == 0 && base == 0) { lo = xs[0]; hi = xs[0]; }
            tp.a = med3f(tp.a, lo, hi);
            tp.b = med3f(tp.b, lo, hi);
        }
    }
    Pair w = tp;
    #pragma unroll
    for (int off = 1; off < 64; off <<= 1) {
        Pair u; u.a = __shfl_up(w.a, off); u.b = __shfl_up(w.b, off);
        if (lane >= off) w = compose(u, w);
    }
    __shared__ Pair wS[TPB / 64];
    if (lane == 63) wS[wid] = w;
    __syncthreads();
    Pair wpre = ident();
    #pragma unroll
    for (int i = 0; i < TPB / 64; ++i) if (i < wid) wpre = compose(wpre, wS[i]);
    Pair up; up.a = __shfl_up(w.a, 1); up.b = __shfl_up(w.b, 1);
    Pair ex = (lane == 0) ? wpre : compose(wpre, up);

    // 4) apply from registers, CACHED float4 stores (L2 merges partial lines)
    Pair fin = compose(E, ex);
    float y = med3f(0.0f, fin.a, fin.b);  // any prefix containing elem 0 is
                                          // constant (a==b): seed 0 is inert
    if (full) {
        #pragma unroll
        for (int v = 0; v < EPT / 4; ++v) {
            float o0, o1, o2, o3;
            { float lo = xs[4*v+0] * k, hi = lo + 1.0f;
              if (v == 0 && base == 0) { lo = xs[0]; hi = xs[0]; }
              y = med3f(y, lo, hi); o0 = y; }
            { float lo = xs[4*v+1] * k, hi = lo + 1.0f; y = med3f(y, lo, hi); o1 = y; }
            { float lo = xs[4*v+2] * k, hi = lo + 1.0f; y = med3f(y, lo, hi); o2 = y; }
            { float lo = xs[4*v+3] * k, hi = lo + 1.0f; y = med3f(y, lo, hi); o3 = y; }
            reinterpret_cast<float4*>(out + base)[v] = make_float4(o0, o1, o2, o3);
        }
    } else {
        #pragma unroll
        for (int j = 0; j < EPT; ++j) {
            if (base + j < n) {
                float lo = xs[j] * k, hi = lo + 1.0f;
                if (j == 0 && base == 0) { lo = xs[0]; hi = xs[0]; }
                y = med3f(y, lo, hi);
                out[base + j] = y;
            }
        }
    }
}

// ========================== host launcher ==================================
extern "C" void kernel_launch(void* const* d_in, const int* in_sizes, int n_in,
                              void* d_out, int out_size, void* d_ws, size_t ws_size,
                              hipStream_t stream) {
    const float* in   = (const float*)d_in[0];   // [T+1], in[0] = p0
    const float* kptr = (const float*)d_in[1];   // scalar weight
    float* out = (float*)d_out;                  // [T+1]
    const int n  = in_sizes[0];
    const int nb = (n + EPB - 1) / EPB;          // 2049 for T = 2^24

    float2* agg = (float2*)d_ws;                 // nb aggregates (16 KB)

    k_reduce<<<nb, TPB, 0, stream>>>(in, kptr, agg, n);
    k_apply <<<nb, TPB, 0, stream>>>(in, kptr, agg, out, n);
}

// Round 8
// 46.328 us; speedup vs baseline: 4.6500x; 1.0693x over previous
//
#include <hip/hip_runtime.h>
#include <math.h>

// y_t = clamp(y_{t-1}, x_t, x_t+1): play operator as associative clamp-scan.
// compose(l, r) = "apply l first, then r" = clamp l's window by r's window.
// min/max/med3-only => exact => any regrouping is bit-identical (deterministic).
//
// Two passes, no atomics:
//   pass 1 (k_reduce): per-block ordered aggregate -> agg[nb] (32 KB, L2)
//   pass 2 (k_apply) : redundant exclusive prefix over agg[] (pipelined L2
//                      loads), clamp chain from registers, then COALESCED
//                      stores via an LDS transpose (thread-contiguous stores
//                      at 64B lane stride are write-through partial-line L2
//                      transactions -> ~2.5 TB/s; coalesced hits ~6.5).

#define TPB 256
#define EPT 16
#define EPB (TPB * EPT)   // 4096 elements per block -> nb = 4097 for T=2^24
#define LPAD 257          // LDS row pitch in words (16*257*4B = 16448 B)

struct Pair { float a, b; };

__device__ __forceinline__ float med3f(float x, float lo, float hi) {
    return __builtin_amdgcn_fmed3f(x, lo, hi);   // clamp(x, lo, hi), lo<=hi
}
__device__ __forceinline__ Pair compose(Pair l, Pair r) {
    Pair o; o.a = med3f(l.a, r.a, r.b); o.b = med3f(l.b, r.a, r.b); return o;
}
__device__ __forceinline__ Pair ident() {
    Pair p; p.a = -INFINITY; p.b = INFINITY; return p;
}

// ---------------- pass 1: per-block ordered aggregate ----------------------
__global__ __launch_bounds__(TPB)
void k_reduce(const float* __restrict__ in, const float* __restrict__ kptr,
              float2* __restrict__ agg, int n) {
    const float k = kptr[0];
    const int tid = threadIdx.x, lane = tid & 63, wid = tid >> 6;
    const int base = blockIdx.x * EPB + tid * EPT;

    Pair p = ident();
    if (base + EPT <= n) {
        #pragma unroll
        for (int v = 0; v < EPT / 4; ++v) {
            float4 f = reinterpret_cast<const float4*>(in + base)[v];
            float xv[4] = {f.x, f.y, f.z, f.w};
            #pragma unroll
            for (int j = 0; j < 4; ++j) {
                float lo = xv[j] * k, hi = lo + 1.0f;
                if (v == 0 && j == 0 && base == 0) { lo = xv[0]; hi = xv[0]; }
                p.a = med3f(p.a, lo, hi);
                p.b = med3f(p.b, lo, hi);
            }
        }
    } else {
        #pragma unroll
        for (int j = 0; j < EPT; ++j) {         // static j: registers only
            if (base + j < n) {
                float x = in[base + j];
                float lo = x * k, hi = lo + 1.0f;
                if (j == 0 && base == 0) { lo = x; hi = x; }
                p.a = med3f(p.a, lo, hi);
                p.b = med3f(p.b, lo, hi);
            }
        }
    }

    // ordered tree-reduce within wave; lane 0 ends with the wave aggregate
    Pair v = p;
    #pragma unroll
    for (int off = 1; off < 64; off <<= 1) {
        Pair u; u.a = __shfl_down(v.a, off); u.b = __shfl_down(v.b, off);
        Pair c = compose(v, u);
        if (lane + off < 64) v = c;
    }
    __shared__ Pair wagg[TPB / 64];
    if (lane == 0) wagg[wid] = v;
    __syncthreads();
    if (tid == 0) {
        Pair b = wagg[0];
        #pragma unroll
        for (int i = 1; i < TPB / 64; ++i) b = compose(b, wagg[i]);
        agg[blockIdx.x] = make_float2(b.a, b.b);
    }
}

// ---------------- pass 2: redundant prefix + apply + LDS-transposed store --
__global__ __launch_bounds__(TPB)
void k_apply(const float* __restrict__ in, const float* __restrict__ kptr,
             const float2* __restrict__ agg, float* __restrict__ out, int n) {
    const float k = kptr[0];
    const int tid = threadIdx.x, lane = tid & 63, wid = tid >> 6;
    const int vid = blockIdx.x;
    const int tile0 = vid * EPB;
    const int base  = tile0 + tid * EPT;

    __shared__ float xpose[EPT * LPAD];   // transpose buffer for stores
    __shared__ Pair wE[TPB / 64];
    __shared__ Pair wS[TPB / 64];

    // 1) issue input loads first (strided reads merge in L1 -> ~6 TB/s)
    float xs[EPT];
    const bool full = (base + EPT <= n);
    if (full) {
        #pragma unroll
        for (int v = 0; v < EPT / 4; ++v) {
            float4 f = reinterpret_cast<const float4*>(in + base)[v];
            xs[4*v+0] = f.x; xs[4*v+1] = f.y; xs[4*v+2] = f.z; xs[4*v+3] = f.w;
        }
    } else {
        #pragma unroll
        for (int j = 0; j < EPT; ++j)           // static j: registers only
            xs[j] = (base + j < n) ? in[base + j] : 0.0f;
    }

    // 2) exclusive block prefix E over agg[0..vid): two batches of 8
    //    independent L2 loads (seg=16 covers vid <= 4096), then compose.
    Pair q = ident();
    {
        const int segd = (vid + TPB - 1) >> 8;          // ceil(vid/256)
        const int seg  = segd > 16 ? segd : 16;
        const int lo   = tid * seg;
        #pragma unroll
        for (int b8 = 0; b8 < 2; ++b8) {
            float ga[8], gb[8];
            #pragma unroll
            for (int i = 0; i < 8; ++i) {               // issue 8 loads
                const int idx = lo + b8 * 8 + i;
                float2 g = (idx < vid) ? agg[idx]
                                       : make_float2(-INFINITY, INFINITY);
                ga[i] = g.x; gb[i] = g.y;
            }
            #pragma unroll
            for (int i = 0; i < 8; ++i) {               // then compose
                Pair r; r.a = ga[i]; r.b = gb[i];
                q = compose(q, r);
            }
        }
        const int hi = (lo + seg < vid) ? lo + seg : vid;
        for (int i = lo + 16; i < hi; ++i) {            // dead for nb<=4097
            float2 g = agg[i];
            Pair r; r.a = g.x; r.b = g.y;
            q = compose(q, r);
        }
    }
    // ordered tree-reduce across the block -> E (same value in all threads)
    Pair v2 = q;
    #pragma unroll
    for (int off = 1; off < 64; off <<= 1) {
        Pair u; u.a = __shfl_down(v2.a, off); u.b = __shfl_down(v2.b, off);
        Pair c = compose(v2, u);
        if (lane + off < 64) v2 = c;
    }
    if (lane == 0) wE[wid] = v2;
    __syncthreads();
    Pair E = wE[0];
    #pragma unroll
    for (int i = 1; i < TPB / 64; ++i) E = compose(E, wE[i]);

    // 3) intra-block exclusive prefix over thread aggregates
    Pair tp = ident();
    #pragma unroll
    for (int j = 0; j < EPT; ++j) {
        if (base + j < n) {
            float lo = xs[j] * k, hi = lo + 1.0f;
            if (j == 0 && base == 0) { lo = xs[0]; hi = xs[0]; }
            tp.a = med3f(tp.a, lo, hi);
            tp.b = med3f(tp.b, lo, hi);
        }
    }
    Pair w = tp;
    #pragma unroll
    for (int off = 1; off < 64; off <<= 1) {
        Pair u; u.a = __shfl_up(w.a, off); u.b = __shfl_up(w.b, off);
        if (lane >= off) w = compose(u, w);
    }
    if (lane == 63) wS[wid] = w;
    __syncthreads();
    Pair wpre = ident();
    #pragma unroll
    for (int i = 0; i < TPB / 64; ++i) if (i < wid) wpre = compose(wpre, wS[i]);
    Pair up; up.a = __shfl_up(w.a, 1); up.b = __shfl_up(w.b, 1);
    Pair ex = (lane == 0) ? wpre : compose(wpre, up);

    // 4) apply from registers
    Pair fin = compose(E, ex);
    float y = med3f(0.0f, fin.a, fin.b);  // any prefix containing elem 0 is
                                          // constant (a==b): seed 0 is inert
    const bool blockFull = (tile0 + EPB <= n);   // uniform across block
    if (blockFull) {
        float o[EPT];
        #pragma unroll
        for (int j = 0; j < EPT; ++j) {
            float lo = xs[j] * k, hi = lo + 1.0f;
            if (j == 0 && base == 0) { lo = xs[0]; hi = xs[0]; }
            y = med3f(y, lo, hi);
            o[j] = y;
        }
        // LDS transpose: word = slot*257 + tid.
        // write side: per j, lanes hit consecutive banks (conflict-free);
        // read side: 2-way aliasing (free per m136).
        #pragma unroll
        for (int j = 0; j < EPT; ++j) xpose[j * LPAD + tid] = o[j];
        __syncthreads();
        // coalesced stores: wave writes contiguous 1 KB per instruction
        #pragma unroll
        for (int c = 0; c < EPT / 4; ++c) {
            const int q4    = c * (TPB * 4) + 4 * tid;  // local element idx
            const int owner = q4 >> 4;                  // source thread
            const int slot  = q4 & 15;                  // 4*(tid%4)
            float4 f;
            f.x = xpose[(slot + 0) * LPAD + owner];
            f.y = xpose[(slot + 1) * LPAD + owner];
            f.z = xpose[(slot + 2) * LPAD + owner];
            f.w = xpose[(slot + 3) * LPAD + owner];
            reinterpret_cast<float4*>(out + tile0)[c * TPB + tid] = f;
        }
    } else {
        #pragma unroll
        for (int j = 0; j < EPT; ++j) {
            if (base + j < n) {
                float lo = xs[j] * k, hi = lo + 1.0f;
                if (j == 0 && base == 0) { lo = xs[0]; hi = xs[0]; }
                y = med3f(y, lo, hi);
                out[base + j] = y;
            }
        }
    }
}

// ========================== host launcher ==================================
extern "C" void kernel_launch(void* const* d_in, const int* in_sizes, int n_in,
                              void* d_out, int out_size, void* d_ws, size_t ws_size,
                              hipStream_t stream) {
    const float* in   = (const float*)d_in[0];   // [T+1], in[0] = p0
    const float* kptr = (const float*)d_in[1];   // scalar weight
    float* out = (float*)d_out;                  // [T+1]
    const int n  = in_sizes[0];
    const int nb = (n + EPB - 1) / EPB;          // 4097 for T = 2^24

    float2* agg = (float2*)d_ws;                 // nb aggregates (32 KB)

    k_reduce<<<nb, TPB, 0, stream>>>(in, kptr, agg, n);
    k_apply <<<nb, TPB, 0, stream>>>(in, kptr, agg, out, n);
}

// Round 9
// 29.629 us; speedup vs baseline: 7.2706x; 1.5636x over previous
//
#include <hip/hip_runtime.h>
#include <math.h>

// y_t = clamp(y_{t-1}, x_t, x_t+1): play operator as associative clamp-scan.
// compose(l, r) = "apply l first, then r" = clamp l's window by r's window.
// min/max/med3-only => exact => any regrouping is bit-identical.
//
// KEY PROPERTY: the composed window is contracting; once its width hits
// exactly 0 (both bounds equal), the function is CONSTANT -- independent of
// everything earlier. For this operator+data that happens within a few
// elements of every block start.
//
//   pass 1 (k_scan1): read input once; per-element block-local window chain
//     (a,b); write a (exact for every element past the block's first-collapse
//     index c); store block aggregate + c. Coalesced stores via LDS transpose.
//   pass 2 (k_fixup): per block, walk agg[] backwards until the suffix
//     composition collapses (terminates at block 0: elem 0 is the constant
//     p0), then recompute only elements [0, c). Tiny.

#define TPB 256
#define EPT 16
#define EPB (TPB * EPT)   // 4096 elements per block -> nb = 4097 for T=2^24
#define LPAD 257          // LDS row pitch in words
#define TPB2 64

struct Pair { float a, b; };

__device__ __forceinline__ float med3f(float x, float lo, float hi) {
    return __builtin_amdgcn_fmed3f(x, lo, hi);   // clamp(x, lo, hi), lo<=hi
}
__device__ __forceinline__ Pair compose(Pair l, Pair r) {
    Pair o; o.a = med3f(l.a, r.a, r.b); o.b = med3f(l.b, r.a, r.b); return o;
}
__device__ __forceinline__ Pair ident() {
    Pair p; p.a = -INFINITY; p.b = INFINITY; return p;
}

// ---------------- pass 1: scan + final-where-collapsed writes --------------
__global__ __launch_bounds__(TPB)
void k_scan1(const float* __restrict__ in, const float* __restrict__ kptr,
             float2* __restrict__ agg, int* __restrict__ cidx,
             float* __restrict__ out, int n) {
    const float k = kptr[0];
    const int tid = threadIdx.x, lane = tid & 63, wid = tid >> 6;
    const int vid = blockIdx.x;
    const int tile0 = vid * EPB;
    const int base  = tile0 + tid * EPT;
    const bool blockFull = (tile0 + EPB <= n);   // uniform across block

    __shared__ Pair  wS[TPB / 64];
    __shared__ int   wmin[TPB / 64];
    __shared__ float xpose[EPT * LPAD];

    // load 16 elements (static indexing only -- rule #20)
    float xs[EPT];
    if (blockFull) {
        #pragma unroll
        for (int v = 0; v < EPT / 4; ++v) {
            float4 f = reinterpret_cast<const float4*>(in + base)[v];
            xs[4*v+0] = f.x; xs[4*v+1] = f.y; xs[4*v+2] = f.z; xs[4*v+3] = f.w;
        }
    } else {
        #pragma unroll
        for (int j = 0; j < EPT; ++j)
            xs[j] = (base + j < n) ? in[base + j] : 0.0f;
    }

    // thread aggregate window
    Pair tp = ident();
    #pragma unroll
    for (int j = 0; j < EPT; ++j) {
        if (base + j < n) {
            float lo = xs[j] * k, hi = lo + 1.0f;
            if (j == 0 && base == 0) { lo = xs[0]; hi = xs[0]; }  // const p0
            tp.a = med3f(tp.a, lo, hi);
            tp.b = med3f(tp.b, lo, hi);
        }
    }

    // wave inclusive scan of thread aggregates
    Pair w = tp;
    #pragma unroll
    for (int off = 1; off < 64; off <<= 1) {
        Pair u; u.a = __shfl_up(w.a, off); u.b = __shfl_up(w.b, off);
        if (lane >= off) w = compose(u, w);
    }
    if (lane == 63) wS[wid] = w;
    __syncthreads();
    Pair wpre = ident();
    #pragma unroll
    for (int i = 0; i < TPB / 64; ++i) if (i < wid) wpre = compose(wpre, wS[i]);
    Pair up; up.a = __shfl_up(w.a, 1); up.b = __shfl_up(w.b, 1);
    Pair ex = (lane == 0) ? wpre : compose(wpre, up);   // block-local excl

    if (tid == 0) {                       // block aggregate
        Pair b = wS[0];
        #pragma unroll
        for (int i = 1; i < TPB / 64; ++i) b = compose(b, wS[i]);
        agg[vid] = make_float2(b.a, b.b);
    }

    // per-element window chain seeded by ex; o[j] = lower bound a.
    // once a==b the value is exact regardless of the inter-block prefix.
    float a = ex.a, bb = ex.b;
    float o[EPT];
    int firstc = EPT;                     // first collapsed j in this thread
    #pragma unroll
    for (int j = 0; j < EPT; ++j) {
        if (base + j < n) {
            float lo = xs[j] * k, hi = lo + 1.0f;
            if (j == 0 && base == 0) { lo = xs[0]; hi = xs[0]; }
            a  = med3f(a,  lo, hi);
            bb = med3f(bb, lo, hi);
            o[j] = a;
            if (firstc == EPT && a == bb) firstc = j;
        } else o[j] = 0.0f;
    }

    // block first-collapse index c = min over threads
    int cand = (firstc < EPT) ? (tid * EPT + firstc) : 0x7fffffff;
    #pragma unroll
    for (int off = 32; off >= 1; off >>= 1)
        cand = min(cand, __shfl_down(cand, off));
    if (lane == 0) wmin[wid] = cand;
    __syncthreads();
    if (tid == 0) {
        int c = wmin[0];
        #pragma unroll
        for (int i = 1; i < TPB / 64; ++i) c = min(c, wmin[i]);
        if (!blockFull)  c = n - tile0;   // tail block: fixup recomputes all
        else if (c > EPB) c = EPB;        // never collapsed
        cidx[vid] = c;
    }

    // store: coalesced via LDS transpose (full blocks)
    if (blockFull) {
        #pragma unroll
        for (int j = 0; j < EPT; ++j) xpose[j * LPAD + tid] = o[j];
        __syncthreads();
        #pragma unroll
        for (int c4 = 0; c4 < EPT / 4; ++c4) {
            const int q4    = c4 * (TPB * 4) + 4 * tid;
            const int owner = q4 >> 4;
            const int slot  = q4 & 15;
            float4 f;
            f.x = xpose[(slot + 0) * LPAD + owner];
            f.y = xpose[(slot + 1) * LPAD + owner];
            f.z = xpose[(slot + 2) * LPAD + owner];
            f.w = xpose[(slot + 3) * LPAD + owner];
            reinterpret_cast<float4*>(out + tile0)[c4 * TPB + tid] = f;
        }
    } else {
        #pragma unroll
        for (int j = 0; j < EPT; ++j)
            if (base + j < n) out[base + j] = o[j];
    }
}

// ---------------- pass 2: fixup of the uncollapsed prefix of each block ----
__global__ __launch_bounds__(TPB2)
void k_fixup(const float* __restrict__ in, const float* __restrict__ kptr,
             const float2* __restrict__ agg, const int* __restrict__ cidx,
             float* __restrict__ out, int n) {
    const int v = blockIdx.x;
    const int c = cidx[v];
    if (c <= 0) return;                       // block 0 lands here (c==0)
    const float k = kptr[0];
    const int lane = threadIdx.x;
    const int tile0 = v * EPB;

    // exact incoming window: compose predecessors' aggregates from nearest
    // backwards until the suffix collapses (block 0 is width-0 via const p0).
    Pair P = ident();
    int j = v - 1;
    while (j >= 0) {
        float2 g = agg[j];
        Pair r; r.a = g.x; r.b = g.y;
        P = compose(r, P);
        if (P.a == P.b) break;
        --j;
    }
    float y = med3f(0.0f, P.a, P.b);          // exact incoming value (v>0)

    // recompute elements [0, c) in 64-wide chunks with wave window scans
    for (int t0 = 0; t0 < c; t0 += TPB2) {
        const int t = t0 + lane;
        const bool valid = (t < c);
        Pair wnd = ident();
        if (valid) {
            float x  = in[tile0 + t];
            float lo = x * k, hi = lo + 1.0f;
            wnd.a = lo; wnd.b = hi;           // elem 0 never reaches fixup
        }
        #pragma unroll
        for (int off = 1; off < 64; off <<= 1) {
            Pair u; u.a = __shfl_up(wnd.a, off); u.b = __shfl_up(wnd.b, off);
            if (lane >= off) wnd = compose(u, wnd);
        }
        float yy = med3f(y, wnd.a, wnd.b);
        if (valid) out[tile0 + t] = yy;
        const int rem = c - t0;
        const int lastl = (rem < TPB2 ? rem : TPB2) - 1;
        y = __shfl(yy, lastl);                // carry to next chunk
    }
}

// ========================== host launcher ==================================
extern "C" void kernel_launch(void* const* d_in, const int* in_sizes, int n_in,
                              void* d_out, int out_size, void* d_ws, size_t ws_size,
                              hipStream_t stream) {
    const float* in   = (const float*)d_in[0];   // [T+1], in[0] = p0
    const float* kptr = (const float*)d_in[1];   // scalar weight
    float* out = (float*)d_out;                  // [T+1]
    const int n  = in_sizes[0];
    const int nb = (n + EPB - 1) / EPB;          // 4097 for T = 2^24

    float2* agg = (float2*)d_ws;                 // nb aggregates
    int*   cidx = (int*)(agg + nb);              // nb collapse indices

    k_scan1<<<nb, TPB,  0, stream>>>(in, kptr, agg, cidx, out, n);
    k_fixup<<<nb, TPB2, 0, stream>>>(in, kptr, agg, cidx, out, n);
}